// Round 9
// baseline (270.584 us; speedup 1.0000x reference)
//
#include <hip/hip_runtime.h>
#include <hip/hip_bf16.h>

#define B_ 16384
#define NF_ 16
#define VOCAB_ 100000
#define ED_ 32
#define NNUM_ 13
#define E_ 8
#define T_ 2
#define H0_ 512
#define H1_ 256
#define TH_ 128
#define D0_ 525
#define K0P 640   // padded K for layer 0 (multiple of 128 -> even # of 64-K-tiles)

typedef __bf16 bf16x8 __attribute__((ext_vector_type(8)));
typedef float  f32x4  __attribute__((ext_vector_type(4)));

typedef __attribute__((address_space(3))) void lds_void;
typedef __attribute__((address_space(1))) const void gbl_void;

__device__ __forceinline__ void load_lds16f(const void* g, void* l) {
  __builtin_amdgcn_global_load_lds((gbl_void*)g, (lds_void*)l, 16, 0, 0);
}

#define BARX                                        \
  do {                                              \
    asm volatile("" ::: "memory");                  \
    __builtin_amdgcn_s_barrier();                   \
    __builtin_amdgcn_sched_barrier(0);              \
    asm volatile("" ::: "memory");                  \
  } while (0)
#define LGKM0                                       \
  do {                                              \
    asm volatile("s_waitcnt lgkmcnt(0)" ::: "memory"); \
    __builtin_amdgcn_sched_barrier(0);              \
  } while (0)

// ---------------- embedding + concat + pad + cast ----------------
__global__ __launch_bounds__(256) void k_embed(const int* __restrict__ cat,
                                               const float* __restrict__ num,
                                               const float* __restrict__ emb,
                                               __hip_bfloat16* __restrict__ x) {
  int b = blockIdx.x;
  int t = threadIdx.x;
  const int* crow = cat + b * NF_;
#pragma unroll
  for (int i = 0; i < 3; ++i) {
    int d = t + i * 256;  // 0..767
    if (d >= K0P) continue;
    float v;
    if (d < 512) {
      int f = d >> 5, c = d & 31;
      v = emb[((long long)(f * VOCAB_ + crow[f])) * ED_ + c];
    } else if (d < D0_) {
      v = num[b * NNUM_ + (d - 512)];
    } else {
      v = 0.f;
    }
    x[(long long)b * K0P + d] = __float2bfloat16(v);
  }
}

// ---------------- weight transpose + pad + cast: W[E][K][N] f32 -> Wp[E][N][KP] bf16 ----------------
__global__ __launch_bounds__(256) void k_wprep(const float* __restrict__ W,
                                               __hip_bfloat16* __restrict__ Wp,
                                               int K, int N, int KP) {
  __shared__ float tile[64][65];
  int k0 = blockIdx.x * 64, n0 = blockIdx.y * 64, e = blockIdx.z;
  int tx = threadIdx.x & 63, ty = threadIdx.x >> 6;
  for (int r = ty; r < 64; r += 4) {
    int k = k0 + r;
    tile[r][tx] = (k < K) ? W[((long long)e * K + k) * N + n0 + tx] : 0.f;
  }
  __syncthreads();
  for (int r = ty; r < 64; r += 4) {
    int n = n0 + r;
    Wp[((long long)e * N + n) * KP + k0 + tx] = __float2bfloat16(tile[tx][r]);
  }
}

// ---------------- BN param folding ----------------
__global__ void k_prep_small(const float* b0, const float* g0, const float* be0,
                             const float* m0, const float* v0,
                             const float* b1, const float* g1, const float* be1,
                             const float* m1, const float* v1,
                             const float* bt1, const float* tg, const float* tb,
                             const float* tm, const float* tv,
                             float* scale0, float* ebias0, float* scale1, float* ebias1,
                             float* tscale, float* tbias) {
  int i = blockIdx.x * 256 + threadIdx.x;
  if (i < H0_) scale0[i] = g0[i] * rsqrtf(v0[i] + 1e-5f);
  if (i < H1_) scale1[i] = g1[i] * rsqrtf(v1[i] + 1e-5f);
  if (i < T_ * TH_) {
    float s = tg[i] * rsqrtf(tv[i] + 1e-5f);
    tscale[i] = s;
    tbias[i] = (bt1[i] - tm[i]) * s + tb[i];
  }
  if (i < E_ * H0_) {
    int n = i & (H0_ - 1);
    float s = g0[n] * rsqrtf(v0[n] + 1e-5f);
    ebias0[i] = (b0[i] - m0[n]) * s + be0[n];
  }
  if (i < E_ * H1_) {
    int n = i & (H1_ - 1);
    float s = g1[n] * rsqrtf(v1[n] + 1e-5f);
    ebias1[i] = (b1[i] - m1[n]) * s + be1[n];
  }
}

// ---------------- gate logits + softmax over 8 experts ----------------
__global__ __launch_bounds__(256) void k_gates(const __hip_bfloat16* __restrict__ x,
                                               const float* __restrict__ Wg,
                                               const float* __restrict__ bg,
                                               float* __restrict__ gates) {
  int gidx = blockIdx.x * 256 + threadIdx.x;
  int b = gidx >> 4, te = gidx & 15;
  int t = te >> 3, e = te & 7;
  const __hip_bfloat16* xr = x + (long long)b * K0P;
  const float* wg = Wg + ((long long)t * D0_) * E_ + e;
  float acc = bg[t * E_ + e];
  int k = 0;
  for (; k + 8 <= D0_; k += 8) {
    bf16x8 xv = *reinterpret_cast<const bf16x8*>(xr + k);
#pragma unroll
    for (int j = 0; j < 8; ++j)
      acc += (float)xv[j] * wg[(long long)(k + j) * E_];
  }
  for (; k < D0_; ++k) acc += __bfloat162float(xr[k]) * wg[(long long)k * E_];
  float mx = acc;
#pragma unroll
  for (int o = 1; o < 8; o <<= 1) mx = fmaxf(mx, __shfl_xor(mx, o));
  float p = __expf(acc - mx);
  float s = p;
#pragma unroll
  for (int o = 1; o < 8; o <<= 1) s += __shfl_xor(s, o);
  gates[((long long)t * B_ + b) * E_ + e] = p / s;
}

// ---------------- persistent grouped GEMM + BN + ReLU -> bf16 ----------------
// Grid = 256 blocks (1/CU), 8 waves. Each block processes TPB output tiles
// (256x256) as ONE continuous K-tile stream: the 8-phase pipeline never drains
// between tiles; prologue once per block; per-tile epilogue bounces through a
// 32 KB spare LDS region (disjoint from staging) while next-tile prefetches
// remain in flight. Tile order (e,ny,mx) with XCD-grouped block mapping.
template <int KC, int NNY, int TPB>
__global__ __launch_bounds__(512, 1) void k_gemmp(
    const __hip_bfloat16* __restrict__ Aall, long long strideAe,
    const __hip_bfloat16* __restrict__ Ball, long long strideBe,
    __hip_bfloat16* __restrict__ Call, long long strideCe,
    const float* __restrict__ scale, const float* __restrict__ ebias,
    int strideEb) {
  constexpr int NK = KC / 64;       // K-tiles per output tile (even)
  constexpr int S = TPB * NK;       // stream length
  constexpr int P = S / 2;          // pairs
  constexpr int PPT = NK / 2;       // pairs per output tile
  constexpr int N = NNY * 256;
  constexpr int LDAB = KC * 2;      // row bytes (A and B both have row length KC)

  __shared__ __align__(16) char SMEM[163840];
  // staging: A slots at [0,65536), B slots at [65536,131072); epilogue at +131072
  char* const Ebuf = SMEM + 131072;

  const int tid = threadIdx.x;
  const int lane = tid & 63;
  const int wid = tid >> 6;
  const int wq_r = wid >> 2, wq_c = wid & 3;

  const int srow = tid >> 3;
  const int swz = ((tid & 7) << 4) ^ ((srow & 7) << 4);

  const int c = blockIdx.x;
  const int vbase = ((c & 7) * 32 + (c >> 3)) * TPB;  // XCD-grouped tile base

  auto decode = [&](int v, int& mx, int& ny, int& e) {
    mx = v & 63;
    int p = v >> 6;
    if (NNY == 2) { ny = p & 1; e = p >> 1; }
    else          { ny = 0;     e = p;      }
  };

  // stage one half-tile (2 gl_lds/thread) of stream tile s
  auto STG = [&](int s, int half, bool isB) {
    const int ot = s / NK, kt = s - ot * NK;
    int mx, ny, e;
    decode(vbase + ot, mx, ny, e);
    const char* base;
    char* dst;
    if (!isB) {
      base = reinterpret_cast<const char*>(Aall + (long long)e * strideAe +
                                           (long long)mx * 256 * KC);
      dst = SMEM + (s & 1) * 32768 + half * 16384;
    } else {
      base = reinterpret_cast<const char*>(Ball + (long long)e * strideBe +
                                           (long long)ny * 256 * KC);
      dst = SMEM + 65536 + (s & 1) * 32768 + half * 16384;
    }
#pragma unroll
    for (int j = 0; j < 2; ++j) {
      const int lrow = srow + j * 64;
      load_lds16f(base + (long long)(half * 128 + lrow) * LDAB + kt * 128 + swz,
                  dst + j * 8192 + tid * 16);
    }
  };

  bf16x8 af[2][4], bq[2][2];
  auto LDA = [&](int slot, int half) {
    const char* Ab = SMEM + slot * 32768 + half * 16384;
#pragma unroll
    for (int kk = 0; kk < 2; ++kk) {
      const int kb = kk * 64 + (lane >> 4) * 16;
#pragma unroll
      for (int m = 0; m < 4; ++m) {
        const int lrow = wq_r * 64 + m * 16 + (lane & 15);
        af[kk][m] = *reinterpret_cast<const bf16x8*>(
            Ab + lrow * 128 + (kb ^ ((lane & 7) << 4)));
      }
    }
  };
  auto LDB = [&](int slot, int half) {
    const char* Bb = SMEM + 65536 + slot * 32768 + half * 16384;
#pragma unroll
    for (int kk = 0; kk < 2; ++kk) {
      const int kb = kk * 64 + (lane >> 4) * 16;
#pragma unroll
      for (int n = 0; n < 2; ++n) {
        const int lrow = wq_c * 32 + n * 16 + (lane & 15);
        bq[kk][n] = *reinterpret_cast<const bf16x8*>(
            Bb + lrow * 128 + (kb ^ ((lane & 7) << 4)));
      }
    }
  };

  f32x4 acc[2][2][4][2];
#pragma unroll
  for (int a = 0; a < 2; ++a)
#pragma unroll
    for (int b = 0; b < 2; ++b)
#pragma unroll
      for (int m = 0; m < 4; ++m)
#pragma unroll
        for (int n = 0; n < 2; ++n) acc[a][b][m][n] = (f32x4){0.f, 0.f, 0.f, 0.f};

#define MMQ(QM, QN)                                                            \
  do {                                                                         \
    __builtin_amdgcn_s_setprio(1);                                             \
    _Pragma("unroll") for (int kk = 0; kk < 2; ++kk)                           \
        _Pragma("unroll") for (int m = 0; m < 4; ++m)                          \
            _Pragma("unroll") for (int n = 0; n < 2; ++n)                      \
                acc[QM][QN][m][n] = __builtin_amdgcn_mfma_f32_16x16x32_bf16(   \
                    af[kk][m], bq[kk][n], acc[QM][QN][m][n], 0, 0, 0);         \
    __builtin_amdgcn_s_setprio(0);                                             \
  } while (0)

  // prologue: stream tile 0 full, then tile1.A0, tile1.B1 -> vmcnt(4)
  STG(0, 0, false); STG(0, 1, false); STG(0, 0, true); STG(0, 1, true);
  STG(1, 0, false); STG(1, 1, true);
  asm volatile("s_waitcnt vmcnt(4)" ::: "memory");
  BARX;

  int ot_done = 0;
#pragma unroll 1
  for (int p = 0; p < P; ++p) {
    const int t1 = 2 * p + 1, t2 = 2 * p + 2, t3 = 2 * p + 3;
    const bool m2 = (t2 < S), m3 = (t3 < S);
    // ---- stream tile t0 = 2p (slot 0) ----
    LDA(0, 0); LDB(0, 0);
    STG(t1, 1, false);
    BARX; LGKM0; MMQ(0, 0); BARX;
    LDB(0, 1);
    STG(t1, 0, true);
    BARX; LGKM0; MMQ(0, 1); BARX;
    LDA(0, 1);
    if (m2) STG(t2, 0, false);
    BARX; LGKM0; MMQ(1, 1); BARX;
    LDB(0, 0);
    if (m2) STG(t2, 1, true);
    BARX; LGKM0; MMQ(1, 0);
    if (m2) { asm volatile("s_waitcnt vmcnt(4)" ::: "memory"); }
    else    { asm volatile("s_waitcnt vmcnt(0)" ::: "memory"); }
    BARX;
    // ---- stream tile t1 (slot 1) ----
    LDA(1, 0); LDB(1, 0);
    if (m2) STG(t2, 1, false);
    BARX; LGKM0; MMQ(0, 0); BARX;
    LDB(1, 1);
    if (m2) STG(t2, 0, true);
    BARX; LGKM0; MMQ(0, 1); BARX;
    LDA(1, 1);
    if (m3) STG(t3, 0, false);
    BARX; LGKM0; MMQ(1, 1); BARX;
    LDB(1, 0);
    if (m3) STG(t3, 1, true);
    BARX; LGKM0; MMQ(1, 0);
    if (m2) { asm volatile("s_waitcnt vmcnt(4)" ::: "memory"); }
    BARX;

    // ---- output-tile boundary: epilogue (staging for next tile stays in flight) ----
    if ((p + 1) % PPT == 0) {
      int mx, ny, e;
      decode(vbase + ot_done, mx, ny, e);
      __hip_bfloat16* C = Call + (long long)e * strideCe;
      const float* eb = ebias + e * strideEb;
      const int m0 = mx * 256, n0 = ny * 256;
#pragma unroll
      for (int Qm = 0; Qm < 2; ++Qm)
#pragma unroll
        for (int Qn = 0; Qn < 2; ++Qn) {
          // write quadrant (128x128) into Ebuf, swizzled
#pragma unroll
          for (int n = 0; n < 2; ++n) {
            const int colc = wq_c * 32 + n * 16 + (lane & 15);
            const int gcol = n0 + Qn * 128 + colc;
            const float s = scale[gcol];
            const float bb = eb[gcol];
#pragma unroll
            for (int m = 0; m < 4; ++m) {
#pragma unroll
              for (int i = 0; i < 4; ++i) {
                const int row = wq_r * 64 + m * 16 + (lane >> 4) * 4 + i;
                const float v = fmaxf(acc[Qm][Qn][m][n][i] * s + bb, 0.f);
                const int byt = row * 256 +
                    ((((colc >> 3) ^ (row & 7)) << 4) | ((colc & 7) << 1));
                *reinterpret_cast<__hip_bfloat16*>(Ebuf + byt) = __float2bfloat16(v);
              }
            }
          }
          BARX;
          // coalesced read + dwordx4 store
#pragma unroll
          for (int it = 0; it < 4; ++it) {
            const int r = it * 32 + (tid >> 4);
            const int c16 = tid & 15;
            const f32x4 d = *reinterpret_cast<const f32x4*>(
                Ebuf + r * 256 + ((c16 ^ (r & 7)) << 4));
            *reinterpret_cast<f32x4*>(
                reinterpret_cast<char*>(C + (long long)(m0 + Qm * 128 + r) * N) +
                (n0 + Qn * 128) * 2 + c16 * 16) = d;
          }
          BARX;
        }
      ++ot_done;
#pragma unroll
      for (int a = 0; a < 2; ++a)
#pragma unroll
        for (int b = 0; b < 2; ++b)
#pragma unroll
          for (int m = 0; m < 4; ++m)
#pragma unroll
            for (int n = 0; n < 2; ++n) acc[a][b][m][n] = (f32x4){0.f, 0.f, 0.f, 0.f};
    }
  }
#undef MMQ
}

// ---------------- gate-weighted combine: fea[t][b][:] = sum_e g[t][b][e]*h1[e][b][:] ----------------
__global__ __launch_bounds__(256) void k_combine(const __hip_bfloat16* __restrict__ h1,
                                                 const float* __restrict__ gates,
                                                 __hip_bfloat16* __restrict__ fea) {
  const int idx = blockIdx.x * 256 + threadIdx.x;  // 0 .. B*H1/8-1
  const int b = idx >> 5, c = idx & 31;
  const f32x4* gp0 = reinterpret_cast<const f32x4*>(gates + (long long)b * E_);
  const f32x4* gp1 = reinterpret_cast<const f32x4*>(gates + ((long long)B_ + b) * E_);
  const f32x4 g0lo = gp0[0], g0hi = gp0[1];
  const f32x4 g1lo = gp1[0], g1hi = gp1[1];

  float a0[8], a1[8];
#pragma unroll
  for (int j = 0; j < 8; ++j) { a0[j] = 0.f; a1[j] = 0.f; }

#pragma unroll
  for (int ee = 0; ee < 8; ++ee) {
    bf16x8 hv = *reinterpret_cast<const bf16x8*>(
        h1 + ((long long)ee * B_ + b) * H1_ + c * 8);
    const float ga = (ee < 4) ? g0lo[ee & 3] : g0hi[ee & 3];
    const float gb = (ee < 4) ? g1lo[ee & 3] : g1hi[ee & 3];
#pragma unroll
    for (int j = 0; j < 8; ++j) {
      float v = (float)hv[j];
      a0[j] += ga * v;
      a1[j] += gb * v;
    }
  }
  bf16x8 o0, o1;
#pragma unroll
  for (int j = 0; j < 8; ++j) { o0[j] = (__bf16)a0[j]; o1[j] = (__bf16)a1[j]; }
  *reinterpret_cast<bf16x8*>(fea + (long long)b * H1_ + c * 8) = o0;
  *reinterpret_cast<bf16x8*>(fea + ((long long)B_ + b) * H1_ + c * 8) = o1;
}

// ---------------- per-task tower MLP + sigmoid ----------------
__global__ __launch_bounds__(256) void k_tower2(
    const __hip_bfloat16* __restrict__ fea, const float* __restrict__ Wt1,
    const float* __restrict__ Wt2, const float* __restrict__ bt2,
    const float* __restrict__ tscale, const float* __restrict__ tbias,
    float* __restrict__ out) {
  __shared__ __align__(16) char Ws[TH_ * 512];  // Ws[h][k] bf16, swizzled
  const int t = blockIdx.y;
  const int tid = threadIdx.x;
  const int lane = tid & 63, wv = tid >> 6;

  const int row = blockIdx.x * 64 + wv * 16 + (lane & 15);
  const int g4 = lane >> 4;

  for (int it = 0; it < 16; ++it) {
    int idx = it * 256 + tid;
    int h = idx & 127, kc = idx >> 7;
    bf16x8 v;
#pragma unroll
    for (int j = 0; j < 8; ++j)
      v[j] = (__bf16)Wt1[((long long)t * H1_ + kc * 8 + j) * TH_ + h];
    int byt = h * 512 + ((kc * 16) ^ ((h & 7) << 4));
    *reinterpret_cast<bf16x8*>(Ws + byt) = v;
  }

  bf16x8 af[8];
  {
    const __hip_bfloat16* fp = fea + ((long long)t * B_ + row) * H1_ + g4 * 8;
#pragma unroll
    for (int c = 0; c < 8; ++c)
      af[c] = *reinterpret_cast<const bf16x8*>(fp + c * 32);
  }
  __syncthreads();

  f32x4 acc[8];
#pragma unroll
  for (int n = 0; n < 8; ++n) acc[n] = (f32x4){0.f, 0.f, 0.f, 0.f};
#pragma unroll
  for (int c = 0; c < 8; ++c) {
    int kb = c * 64 + g4 * 16;
#pragma unroll
    for (int n = 0; n < 8; ++n) {
      int hrow = n * 16 + (lane & 15);
      bf16x8 bv = *reinterpret_cast<const bf16x8*>(Ws + hrow * 512 + (kb ^ ((hrow & 7) << 4)));
      acc[n] = __builtin_amdgcn_mfma_f32_16x16x32_bf16(af[c], bv, acc[n], 0, 0, 0);
    }
  }

  float part[4] = {0.f, 0.f, 0.f, 0.f};
#pragma unroll
  for (int n = 0; n < 8; ++n) {
    int col = n * 16 + (lane & 15);
    float s = tscale[t * TH_ + col], bb = tbias[t * TH_ + col], w2 = Wt2[t * TH_ + col];
#pragma unroll
    for (int i = 0; i < 4; ++i)
      part[i] += fmaxf(acc[n][i] * s + bb, 0.f) * w2;
  }
#pragma unroll
  for (int o = 1; o < 16; o <<= 1) {
#pragma unroll
    for (int i = 0; i < 4; ++i) part[i] += __shfl_xor(part[i], o);
  }
  if ((lane & 15) == 0) {
    int rbase = blockIdx.x * 64 + wv * 16 + g4 * 4;
    float b2 = bt2[t];
#pragma unroll
    for (int i = 0; i < 4; ++i) {
      float z = part[i] + b2;
      out[(long long)t * B_ + rbase + i] = 1.f / (1.f + __expf(-z));
    }
  }
}

extern "C" void kernel_launch(void* const* d_in, const int* in_sizes, int n_in,
                              void* d_out, int out_size, void* d_ws, size_t ws_size,
                              hipStream_t stream) {
  const int*   cat = (const int*)d_in[0];
  const float* num = (const float*)d_in[1];
  const float* emb = (const float*)d_in[3];
  const float* W0  = (const float*)d_in[4];
  const float* b0  = (const float*)d_in[5];
  const float* g0  = (const float*)d_in[6];
  const float* be0 = (const float*)d_in[7];
  const float* m0  = (const float*)d_in[8];
  const float* v0  = (const float*)d_in[9];
  const float* W1  = (const float*)d_in[10];
  const float* b1  = (const float*)d_in[11];
  const float* g1  = (const float*)d_in[12];
  const float* be1 = (const float*)d_in[13];
  const float* m1  = (const float*)d_in[14];
  const float* v1  = (const float*)d_in[15];
  const float* Wg  = (const float*)d_in[16];
  const float* bg  = (const float*)d_in[17];
  const float* Wt1 = (const float*)d_in[18];
  const float* bt1 = (const float*)d_in[19];
  const float* tg  = (const float*)d_in[20];
  const float* tb  = (const float*)d_in[21];
  const float* tm  = (const float*)d_in[22];
  const float* tv  = (const float*)d_in[23];
  const float* Wt2 = (const float*)d_in[24];
  const float* bt2 = (const float*)d_in[25];
  float* out = (float*)d_out;

  char* ws = (char*)d_ws;
  if (ws_size < 247496704ULL) return;

  __hip_bfloat16* x_bf = (__hip_bfloat16*)(ws + 0ULL);            // 16384*640*2
  __hip_bfloat16* W0p  = (__hip_bfloat16*)(ws + 20971520ULL);     // 8*512*640*2
  __hip_bfloat16* W1p  = (__hip_bfloat16*)(ws + 26214400ULL);     // 8*256*512*2
  float* gates   = (float*)(ws + 28311552ULL);                    // 2*16384*8*4
  float* scale0  = (float*)(ws + 29360128ULL);
  float* ebias0  = (float*)(ws + 29362176ULL);
  float* scale1  = (float*)(ws + 29378560ULL);
  float* ebias1  = (float*)(ws + 29379584ULL);
  float* tscale  = (float*)(ws + 29387776ULL);
  float* tbias   = (float*)(ws + 29388800ULL);
  __hip_bfloat16* h0  = (__hip_bfloat16*)(ws + 29392896ULL);      // 8*16384*512*2
  __hip_bfloat16* h1  = (__hip_bfloat16*)(ws + 163610624ULL);     // 8*16384*256*2
  __hip_bfloat16* fea = (__hip_bfloat16*)(ws + 230719488ULL);     // 2*16384*256*2

  // weight prep + BN folding
  k_wprep<<<dim3(K0P / 64, H0_ / 64, E_), 256, 0, stream>>>(W0, W0p, D0_, H0_, K0P);
  k_wprep<<<dim3(H0_ / 64, H1_ / 64, E_), 256, 0, stream>>>(W1, W1p, H0_, H1_, H0_);
  k_prep_small<<<16, 256, 0, stream>>>(b0, g0, be0, m0, v0, b1, g1, be1, m1, v1,
                                       bt1, tg, tb, tm, tv,
                                       scale0, ebias0, scale1, ebias1, tscale, tbias);
  // embedding + concat
  k_embed<<<B_, 256, 0, stream>>>(cat, num, emb, x_bf);
  // gates
  k_gates<<<B_ * 16 / 256, 256, 0, stream>>>(x_bf, Wg, bg, gates);
  // layer 0: [B,640] x [E,512,640]^T -> h0 [E,B,512]   (persistent, 1024 tiles / 256 blocks)
  k_gemmp<K0P, 2, 4><<<256, 512, 0, stream>>>(
      x_bf, 0LL, W0p, (long long)H0_ * K0P,
      h0, (long long)B_ * H0_, scale0, ebias0, H0_);
  // layer 1: h0 [E,B,512] x [E,256,512]^T -> h1 [E,B,256]  (512 tiles / 256 blocks)
  k_gemmp<H0_, 1, 2><<<256, 512, 0, stream>>>(
      h0, (long long)B_ * H0_, W1p, (long long)H1_ * H0_,
      h1, (long long)B_ * H1_, scale1, ebias1, H1_);
  // gate-weighted combine (both tasks, one h1 pass)
  k_combine<<<B_ * H1_ / 8 / 256, 256, 0, stream>>>(h1, gates, fea);
  // per-task tower MLP + sigmoid
  k_tower2<<<dim3(B_ / 64, T_), 256, 0, stream>>>(fea, Wt1, Wt2, bt2,
                                                  tscale, tbias, out);
}